// Round 11
// baseline (321.706 us; speedup 1.0000x reference)
//
#include <hip/hip_runtime.h>
#include <math.h>

namespace {
constexpr int D     = 192;
constexpr int HW    = 256 * 512;   // 131072 = 2^17
constexpr int TOTAL = 2 * HW;      // 262144 pixels
constexpr unsigned ROWB = (unsigned)HW * 4u;   // bytes per depth slice (512 KB)

typedef __attribute__((address_space(3))) char lds_char;

// Correctly-rounded s/5 in 3 ops (Markstein): bit-exact vs IEEE s/5.0f for
// all normal s >= 0 (our s in [0,5)).
__device__ __forceinline__ float div5(float s) {
    const float c = 0.2f;
    float q = s * c;
    float r = __builtin_fmaf(-5.0f, q, s);
    return __builtin_fmaf(r, c, q);
}

__device__ __forceinline__ bool in_range(int d, int lo, unsigned width) {
    return (unsigned)(d - lo) <= width;
}

// Streaming modal-mask state machine, bit-exact vs the numpy reference.
struct Machine {
    float bprev, maxv;
    int   index, last_fall, index_l, index_r;
    bool  r_found;

    __device__ __forceinline__ void init() {
        bprev = 1.0f;          // "ones" prepend: diff at d=0 is b0 - 1 < 0 -> fall
        maxv  = -INFINITY;
        index = 0; last_fall = 0; index_l = 0;
        index_r = D - 1;       // default: rise at virtual position D (append ones)
        r_found = false;
    }

    __device__ __forceinline__ void step(int d, float b) {
        float diff = b - bprev;
        bool fall  = diff < 0.0f;
        last_fall  = fall ? d : last_fall;               // strict fall
        bool am    = b > maxv;                           // first-occurrence argmax
        maxv       = am ? b : maxv;
        index      = am ? d : index;
        index_l    = am ? last_fall : index_l;           // last fall <= new argmax
        bool rise  = (diff > 0.0f) & (!r_found) & (!am); // first strict rise AFTER argmax
        index_r    = am ? (D - 1) : (rise ? (d - 1) : index_r);
        r_found    = am ? false : (r_found | rise);
        bprev      = b;
    }

    __device__ __forceinline__ void finish(int& lo, unsigned& wd) const {
        int r = min(index_r - index, index - index_l);
        int t = 2 * index - index_r - index_l;
        bool valid = (t > -3) && (t < 3);
        lo = valid ? index_l : (index - r);
        int hi = valid ? index_r : (index + r);
        wd = (unsigned)(hi - lo);
    }
};
} // namespace

// Block-cooperative LDS-ring streaming (m201/8-phase pattern, streaming form).
// Ring: 32 slots x 1 KB; slot s holds the depth-row (256 block pixels) of
// stream element e (depth = e+2 lookahead), s = e % 32. Wave w stages element
// 4r+28+w with ONE width-16 global_load_lds (64 lanes x 16 B = 1 KB fully
// contiguous -- the m97-proven DMA mode, NOT R8's width-4 per-lane mode).
// Counted vmcnt(6) + raw s_barrier per round: each wave confirms only ITS
// OWN oldest DMA; the barrier aggregates all 4 waves' confirmations (m201
// correctness argument). vmcnt never drains to 0 inside the loop.
// Slot safety: the slot written at round r ((4r+28+w)&31) is exactly the slot
// consumed at round r-1; barrier(r) + the compile-time fence after it order
// the write after ALL waves' round-(r-1) reads.
//
// Why this shape: pipeline depth lives in LDS, not VGPRs -- register demand
// ~40, under the 64-VGPR allocator wall that spilled every deeper VGPR
// pipeline (R2/R4/R5: 280-290 MB scratch). 16x fewer load instructions;
// 28-element load->use distance.
extern "C" __global__ void __launch_bounds__(256, 4)
dme_kernel(const float* __restrict__ x, float* __restrict__ out)
{
    __shared__ float ring[32 * 256];               // 32 KB; 4 blocks/CU = 128 KB

    const int tid  = threadIdx.x;
    const int w    = tid >> 6;                     // wave id 0..3
    const int lane = tid & 63;
    const int n    = blockIdx.x >> 9;              // 512 blocks per image
    const int hw0  = (blockIdx.x & 511) << 8;      // block's first pixel
    const int hw   = hw0 | tid;
    const float* __restrict__ xn = x + (size_t)n * (size_t)(D * HW);
    const char* xb = (const char*)xn;
    const unsigned hb4    = (unsigned)hw0 * 4u;
    const unsigned lane16 = (unsigned)lane << 4;
    const float* __restrict__ col = xn + hw;       // per-thread column base

    const float x0 = col[0];
    const float x1 = col[HW];

    // One DMA: depth-row of element e -> ring slot e%32. Per-lane source is
    // 16 B contiguous (pixels hw0+4l..hw0+4l+3); LDS dest is the uniform
    // slot base (HW writes base + lane*16). Elements >= 190 clamp the source
    // depth to 191; their values are statically zeroed at consume.
    auto stage = [&](int e) {
        const int dep = min(e + 2, D - 1);
        __builtin_amdgcn_global_load_lds(
            (__attribute__((address_space(1))) void*)
                (xb + (unsigned)dep * ROWB + hb4 + lane16),
            (__attribute__((address_space(3))) void*)
                ((lds_char*)ring + (unsigned)((e & 31) << 10)),
            16, 0, 0);
    };

    // 48 rounds x 4 elements; staged 7 rounds (28 elements) ahead.
    auto run_pass = [&](auto&& f) {
        #pragma unroll
        for (int i = 0; i < 7; ++i) stage(4 * i + w);
        for (int r = 0; r < 48; ++r) {
            // 7 of my DMAs outstanding; the oldest is the one consumed this
            // round. Confirm it, keep 6 in flight. Memory clobber pins the
            // LDS reads below this wait (no hoisting).
            asm volatile("s_waitcnt vmcnt(6)" ::: "memory");
            __builtin_amdgcn_s_barrier();          // aggregate confirmations
            // Compile-time fence: the builtin barrier may not be a compiler
            // memory fence; this pins the stage() DMA below the barrier so
            // it cannot overwrite the slot other waves read last round.
            asm volatile("" ::: "memory");
            const int base = ((r & 7) << 10) + tid;
            float v0 = ring[base];
            float v1 = ring[base + 256];
            float v2 = ring[base + 512];
            float v3 = ring[base + 768];
            const int d0 = 4 * r;
            f(d0 + 0, v0);
            f(d0 + 1, v1);
            f(d0 + 2, (d0 + 2 >= D - 2) ? 0.0f : v2);   // elements 190,191 -> 0
            f(d0 + 3, (d0 + 3 >= D - 2) ? 0.0f : v3);
            stage(d0 + 28 + w);                    // rounds 41..47: harmless
        }                                          //   dummies (slots proven dead)
        // Drain the 7 tail dummies so the next pass's counted waits start
        // from zero (and no stale DMA can land late into a reused slot).
        asm volatile("s_waitcnt vmcnt(0)" ::: "memory");
        __builtin_amdgcn_s_barrier();
        asm volatile("" ::: "memory");
    };

    // ================= pass 1: modal mask of blur(x) =================
    Machine m1; m1.init();
    {
        float a0 = 0.f, a1 = 0.f, a2 = x0, a3 = x1;
        run_pass([&](int d, float xv) {
            // exact left-to-right window sum, matching reference add order
            float s = a0 + a1; s += a2; s += a3; s += xv;
            m1.step(d, div5(s));
            a0 = a1; a1 = a2; a2 = a3; a3 = xv;
        });
    }
    int lo1; unsigned wd1; m1.finish(lo1, wd1);

    // ====== pass 2: modal mask of blur(x)*~mask1, plus y-sums ======
    Machine m2; m2.init();
    float sum_y = 0.f, wsum_y = 0.f;
    {
        float a0 = 0.f, a1 = 0.f, a2 = x0, a3 = x1;
        float fd = 0.0f;
        run_pass([&](int d, float xv) {
            float s = a0 + a1; s += a2; s += a3; s += xv;
            float b = div5(s);
            bool in1 = in_range(d, lo1, wd1);
            m2.step(d, in1 ? 0.0f : b);          // x_blur2 = x_blur * ~mask1
            float xm = in1 ? a2 : 0.f;           // y = x*mask1; x[d] == a2
            sum_y += xm;
            wsum_y = __builtin_fmaf(xm, fd, wsum_y);  // fma(0,fd,w)==w exact
            a0 = a1; a1 = a2; a2 = a3; a3 = xv; fd += 1.0f;
        });
    }
    int lo2; unsigned wd2; m2.finish(lo2, wd2);

    // ========= pass 3: z-sums (z = x * ~mask1 * mask2nd) =========
    // Exact interval fold (skipped terms are exact zeros; IEEE identity),
    // 4-wide load batching, ascending add order -- verified R7/R9.
    float sum_z = 0.f, wsum_z = 0.f;
    {
        const int dend = lo2 + (int)wd2;       // inclusive; within [0, D-1]
        auto acc = [&](float xv, int dd) {
            bool  zz = !in_range(dd, lo1, wd1);
            float xm = zz ? xv : 0.0f;
            sum_z += xm;
            wsum_z = __builtin_fmaf(xm, (float)dd, wsum_z);
        };
        int dd = lo2;
        for (; dd + 3 <= dend; dd += 4) {
            float v0 = col[(size_t)(dd + 0) * HW];
            float v1 = col[(size_t)(dd + 1) * HW];
            float v2 = col[(size_t)(dd + 2) * HW];
            float v3 = col[(size_t)(dd + 3) * HW];
            acc(v0, dd + 0); acc(v1, dd + 1);
            acc(v2, dd + 2); acc(v3, dd + 3);
        }
        for (; dd <= dend; ++dd) acc(col[(size_t)dd * HW], dd);
    }

    bool  v = (sum_y >= sum_z);
    float S = v ? sum_y  : sum_z;
    float W = v ? wsum_y : wsum_z;
    out[hw + n * HW] = W / S;    // == sum(xm*d)/sum(xm)
}

extern "C" void kernel_launch(void* const* d_in, const int* in_sizes, int n_in,
                              void* d_out, int out_size, void* d_ws, size_t ws_size,
                              hipStream_t stream)
{
    const float* x   = (const float*)d_in[0];
    float*       out = (float*)d_out;
    dim3 block(256), grid(TOTAL / 256);          // 1024 blocks, 4 blocks/CU
    hipLaunchKernelGGL(dme_kernel, grid, block, 0, stream, x, out);
}